// Round 9
// baseline (312.625 us; speedup 1.0000x reference)
//
#include <hip/hip_runtime.h>
#include <math.h>

#define XG 432
#define YG 496
#define NPTS 32
#define COUT 64
#define ROWH 72      // halfwords per LDS h1 row (144 B)
#define STROW 434    // scatter LDS row stride in halfwords (432 + 2 pad)

typedef __attribute__((ext_vector_type(8))) __bf16 bf16x8;
typedef __attribute__((ext_vector_type(2))) __bf16 bf16x2;
typedef __attribute__((ext_vector_type(16))) float f32x16;
typedef __attribute__((ext_vector_type(4))) float f32x4;
typedef __attribute__((ext_vector_type(4))) unsigned short u16x4;

union ABFrag { bf16x8 v; unsigned short s[8]; unsigned u[4]; };

__device__ __forceinline__ unsigned short f2bf(float f) {
    unsigned u = __builtin_bit_cast(unsigned, f);
    u = (u + 0x7fffu + ((u >> 16) & 1u)) >> 16;
    return (unsigned short)u;
}

__device__ __forceinline__ float bf2f(unsigned short h) {
    unsigned u = ((unsigned)h) << 16;
    return __builtin_bit_cast(float, u);
}

__device__ __forceinline__ unsigned pack_bf16(float a, float b) {
#if __has_builtin(__builtin_amdgcn_cvt_pk_bf16_f32)
    bf16x2 r = __builtin_amdgcn_cvt_pk_bf16_f32(a, b);
    return __builtin_bit_cast(unsigned, r);
#else
    return (unsigned)f2bf(a) | ((unsigned)f2bf(b) << 16);
#endif
}

// ---------------------------------------------------------------------------
// Precompute (block 0) + winner=-1 init (all blocks). BN folded into weights:
//   W1' = W1 * s1, bias bb1 appended as feature k=6 (K padded 7->16)
//   W2' = W2 * s2, bias bb2 added after max-pool (exact: s2 const per channel)
//   h1 LDS position k' holds channel sigma(k') = (k'&1)*32 + (k'>>1).
// ---------------------------------------------------------------------------
__global__ __launch_bounds__(256) void precompute_kernel(
    const float* __restrict__ W1,
    const float* __restrict__ g1, const float* __restrict__ b1,
    const float* __restrict__ m1, const float* __restrict__ v1,
    const float* __restrict__ W2,
    const float* __restrict__ g2, const float* __restrict__ b2,
    const float* __restrict__ m2, const float* __restrict__ v2,
    unsigned short* __restrict__ w1f,   // [2][64][8]
    unsigned short* __restrict__ w2f,   // [2][4][64][8]
    float* __restrict__ bb2v,           // [64]
    int4* __restrict__ winner4, int nwin4)
{
    const int gid = blockIdx.x * 256 + threadIdx.x;
    if (gid < nwin4) winner4[gid] = make_int4(-1, -1, -1, -1);
    if (blockIdx.x != 0) return;

    const int t = threadIdx.x;
    if (t < 128) {
        const int tt = t >> 6, lane = t & 63;
        const int half = lane >> 5, l31 = lane & 31;
        unsigned short vals[8] = {0,0,0,0,0,0,0,0};
        if (half == 0) {
            const int co = tt * 32 + l31;
            const float s1  = g1[co] * rsqrtf(v1[co] + 1e-5f);
            const float bb1 = b1[co] - m1[co] * s1;
            for (int k = 0; k < 6; ++k) vals[k] = f2bf(W1[co * 6 + k] * s1);
            vals[6] = f2bf(bb1);
        }
        for (int j = 0; j < 8; ++j) w1f[(tt * 64 + lane) * 8 + j] = vals[j];
    }
    if (t < 64) {
        const float s2 = g2[t] * rsqrtf(v2[t] + 1e-5f);
        bb2v[t] = b2[t] - m2[t] * s2;
    }
    for (int idx = t; idx < 512; idx += 256) {
        const int tt   = idx >> 8;
        const int kt   = (idx >> 6) & 3;
        const int lane = idx & 63;
        const int half = lane >> 5, l31 = lane & 31;
        const int co = tt * 32 + l31;
        const float s2 = g2[co] * rsqrtf(v2[co] + 1e-5f);
        for (int j = 0; j < 8; ++j) {
            const int kp = kt * 16 + half * 8 + j;
            const int ci = ((kp & 1) << 5) | (kp >> 1);   // sigma(kp)
            w2f[((tt * 4 + kt) * 64 + lane) * 8 + j] = f2bf(W2[co * COUT + ci] * s2);
        }
    }
}

// ---------------------------------------------------------------------------
// TWO pillars per wave (unchanged from R8). MLP1+MLP2 via mfma 32x32x16 bf16.
// ---------------------------------------------------------------------------
__global__ __launch_bounds__(256) void pillar_mlp_kernel(
    const float* __restrict__ pillars,   // (P, 32, 4)
    const int*   __restrict__ coors,     // (P, 4) : b, x, y, 0
    const int*   __restrict__ npp,       // (P,)
    const unsigned short* __restrict__ w1f,
    const unsigned short* __restrict__ w2f,
    const float* __restrict__ bb2v,
    float* __restrict__ pooled,          // (P, 64)
    int*   __restrict__ winner,          // (B, YG, XG), pre-set to -1
    int P)
{
    __shared__ unsigned int sh1[8][NPTS * (ROWH / 2)];   // 36864 B

    const int w    = threadIdx.x >> 6;
    const int lane = threadIdx.x & 63;
    const int half = lane >> 5;
    const int l31  = lane & 31;
    const int pa   = blockIdx.x * 8 + w * 2;
    const int pb   = pa + 1;
    const int pac  = (pb < P) ? pa : (P >= 2 ? P - 2 : 0);

    const float4 pt = ((const float4*)pillars)[(size_t)pac * NPTS + lane];
    const int    np_my = npp[pac + half];
    const int4   crA = ((const int4*)coors)[pac];
    const int4   crB = ((const int4*)coors)[pac + 1];
    const bf16x8* w1v = (const bf16x8*)w1f;
    const bf16x8 b1f0 = w1v[lane];
    const bf16x8 b1f1 = w1v[64 + lane];

    float sx = pt.x, sy = pt.y, sz = pt.z;
    #pragma unroll
    for (int m = 1; m <= 16; m <<= 1) {
        sx += __shfl_xor(sx, m);
        sy += __shfl_xor(sy, m);
        sz += __shfl_xor(sz, m);
    }
    const float inv_np = 1.0f / (float)np_my;
    const float cx = sx * inv_np, cy = sy * inv_np, cz = sz * inv_np;
    const int   mygx = half ? crB.y : crA.y;
    const int   mygy = half ? crB.z : crA.z;
    const float px = (float)mygx * 0.16f + 0.08f;
    const float py = (float)mygy * 0.16f + (-39.60f);

    const bool on = (l31 < np_my);
    const unsigned f0 = on ? pack_bf16(pt.z,      pt.x - cx) : 0u;
    const unsigned f1 = on ? pack_bf16(pt.y - cy, pt.z - cz) : 0u;
    const unsigned f2 = on ? pack_bf16(pt.x - px, pt.y - py) : 0u;

    const unsigned g0 = __shfl_xor(f0, 32);
    const unsigned g1 = __shfl_xor(f1, 32);
    const unsigned g2 = __shfl_xor(f2, 32);

    ABFrag aA, aB;
    aA.u[0] = half ? 0u : f0;
    aA.u[1] = half ? 0u : f1;
    aA.u[2] = half ? 0u : f2;
    aA.u[3] = half ? 0u : 0x00003F80u;
    aB.u[0] = half ? 0u : g0;
    aB.u[1] = half ? 0u : g1;
    aB.u[2] = half ? 0u : g2;
    aB.u[3] = aA.u[3];

    f32x16 z;
    #pragma unroll
    for (int i = 0; i < 16; ++i) z[i] = 0.f;

    unsigned int* rowA = sh1[w * 2];
    unsigned int* rowB = sh1[w * 2 + 1];
    {
        f32x16 dA0 = __builtin_amdgcn_mfma_f32_32x32x16_bf16(aA.v, b1f0, z, 0, 0, 0);
        f32x16 dA1 = __builtin_amdgcn_mfma_f32_32x32x16_bf16(aA.v, b1f1, z, 0, 0, 0);
        #pragma unroll
        for (int r = 0; r < 16; ++r) {
            const int point = (r & 3) + 8 * (r >> 2) + 4 * half;
            rowA[point * (ROWH / 2) + l31] =
                pack_bf16(fmaxf(dA0[r], 0.f), fmaxf(dA1[r], 0.f));
        }
    }
    {
        f32x16 dB0 = __builtin_amdgcn_mfma_f32_32x32x16_bf16(aB.v, b1f0, z, 0, 0, 0);
        f32x16 dB1 = __builtin_amdgcn_mfma_f32_32x32x16_bf16(aB.v, b1f1, z, 0, 0, 0);
        #pragma unroll
        for (int r = 0; r < 16; ++r) {
            const int point = (r & 3) + 8 * (r >> 2) + 4 * half;
            rowB[point * (ROWH / 2) + l31] =
                pack_bf16(fmaxf(dB0[r], 0.f), fmaxf(dB1[r], 0.f));
        }
    }

    const unsigned short* rhA = (const unsigned short*)rowA;
    const unsigned short* rhB = (const unsigned short*)rowB;
    bf16x8 a2A[4], a2B[4];
    #pragma unroll
    for (int kt = 0; kt < 4; ++kt) {
        a2A[kt] = *(const bf16x8*)(rhA + l31 * ROWH + kt * 16 + half * 8);
        a2B[kt] = *(const bf16x8*)(rhB + l31 * ROWH + kt * 16 + half * 8);
    }

    const bf16x8* w2v = (const bf16x8*)w2f;
    float mxA[2], mxB[2];
    #pragma unroll
    for (int tile = 0; tile < 2; ++tile) {
        bf16x8 bt0 = w2v[(tile * 4 + 0) * 64 + lane];
        bf16x8 bt1 = w2v[(tile * 4 + 1) * 64 + lane];
        bf16x8 bt2 = w2v[(tile * 4 + 2) * 64 + lane];
        bf16x8 bt3 = w2v[(tile * 4 + 3) * 64 + lane];
        f32x16 cA = z, cB = z;
        cA = __builtin_amdgcn_mfma_f32_32x32x16_bf16(a2A[0], bt0, cA, 0, 0, 0);
        cB = __builtin_amdgcn_mfma_f32_32x32x16_bf16(a2B[0], bt0, cB, 0, 0, 0);
        cA = __builtin_amdgcn_mfma_f32_32x32x16_bf16(a2A[1], bt1, cA, 0, 0, 0);
        cB = __builtin_amdgcn_mfma_f32_32x32x16_bf16(a2B[1], bt1, cB, 0, 0, 0);
        cA = __builtin_amdgcn_mfma_f32_32x32x16_bf16(a2A[2], bt2, cA, 0, 0, 0);
        cB = __builtin_amdgcn_mfma_f32_32x32x16_bf16(a2B[2], bt2, cB, 0, 0, 0);
        cA = __builtin_amdgcn_mfma_f32_32x32x16_bf16(a2A[3], bt3, cA, 0, 0, 0);
        cB = __builtin_amdgcn_mfma_f32_32x32x16_bf16(a2B[3], bt3, cB, 0, 0, 0);
        float a0 = fmaxf(fmaxf(fmaxf(cA[0], cA[1]), fmaxf(cA[2], cA[3])),
                         fmaxf(fmaxf(cA[4], cA[5]), fmaxf(cA[6], cA[7])));
        float a1 = fmaxf(fmaxf(fmaxf(cA[8], cA[9]), fmaxf(cA[10], cA[11])),
                         fmaxf(fmaxf(cA[12], cA[13]), fmaxf(cA[14], cA[15])));
        mxA[tile] = fmaxf(a0, a1);
        float b0 = fmaxf(fmaxf(fmaxf(cB[0], cB[1]), fmaxf(cB[2], cB[3])),
                         fmaxf(fmaxf(cB[4], cB[5]), fmaxf(cB[6], cB[7])));
        float b1_ = fmaxf(fmaxf(fmaxf(cB[8], cB[9]), fmaxf(cB[10], cB[11])),
                          fmaxf(fmaxf(cB[12], cB[13]), fmaxf(cB[14], cB[15])));
        mxB[tile] = fmaxf(b0, b1_);
    }
    mxA[0] = fmaxf(mxA[0], __shfl_xor(mxA[0], 32));
    mxA[1] = fmaxf(mxA[1], __shfl_xor(mxA[1], 32));
    mxB[0] = fmaxf(mxB[0], __shfl_xor(mxB[0], 32));
    mxB[1] = fmaxf(mxB[1], __shfl_xor(mxB[1], 32));

    if (pb < P) {
        const float bb2 = bb2v[lane];
        pooled[(size_t)pa * COUT + lane] = (half ? mxA[1] : mxA[0]) + bb2;
        pooled[(size_t)pb * COUT + lane] = (half ? mxB[1] : mxB[0]) + bb2;
        if (lane == 0)
            atomicMax(&winner[crA.x * (YG * XG) + crA.z * XG + crA.y], pa);
        if (lane == 32)
            atomicMax(&winner[crB.x * (YG * XG) + crB.z * XG + crB.y], pb);
    }
}

// ---------------------------------------------------------------------------
// Row scatter: one block per (b, y). Gather winner rows cell-major (cheap,
// 256 B-coalesced), stage the full 432-cell row in LDS as bf16 (by channel),
// then store each (ch, y) output row as a CONTIGUOUS 1.7 KB linear NT stream
// (64 lanes x 16 B). Linear per-plane streams fix HBM write efficiency.
// ---------------------------------------------------------------------------
__global__ __launch_bounds__(256) void scatter_kernel(
    const float4* __restrict__ pooled4,   // (P, 64) viewed as float4[P*16]
    const int4*   __restrict__ winner4,   // (B, YG, XG/4)
    f32x4* __restrict__ out)              // (B, 64, YG, XG/4)
{
    __shared__ int swn[XG];                       // 1728 B
    __shared__ unsigned short st[COUT * STROW];   // 55552 B

    const int bid = blockIdx.x;
    const int y   = bid % YG;
    const int b   = bid / YG;
    const int tid = threadIdx.x;

    if (tid < XG / 4)
        ((int4*)swn)[tid] = winner4[(b * YG + y) * (XG / 4) + tid];
    __syncthreads();

    // gather: 432 cells x 16 float4 = 6912 = 27 x 256
    #pragma unroll 3
    for (int i = 0; i < 27; ++i) {
        const int f    = i * 256 + tid;
        const int cell = f >> 4, q = f & 15;
        const int wn   = swn[cell];
        float4 v = make_float4(0.f, 0.f, 0.f, 0.f);
        if (wn >= 0) v = pooled4[(size_t)wn * 16 + q];
        st[(4 * q + 0) * STROW + cell] = f2bf(v.x);
        st[(4 * q + 1) * STROW + cell] = f2bf(v.y);
        st[(4 * q + 2) * STROW + cell] = f2bf(v.z);
        st[(4 * q + 3) * STROW + cell] = f2bf(v.w);
    }
    __syncthreads();

    // store: 64 ch x 108 float4 = 6912 = 27 x 256; each wave writes one
    // contiguous 1 KB span of a single (ch, y) row.
    #pragma unroll 3
    for (int i = 0; i < 27; ++i) {
        const int f  = i * 256 + tid;
        const int ch = f / 108;
        const int xq = f - ch * 108;
        const u16x4 h = *(const u16x4*)&st[ch * STROW + xq * 4];
        f32x4 v;
        v[0] = bf2f(h[0]); v[1] = bf2f(h[1]);
        v[2] = bf2f(h[2]); v[3] = bf2f(h[3]);
        __builtin_nontemporal_store(v,
            &out[((size_t)(b * COUT + ch) * YG + y) * (XG / 4) + xq]);
    }
}

extern "C" void kernel_launch(void* const* d_in, const int* in_sizes, int n_in,
                              void* d_out, int out_size, void* d_ws, size_t ws_size,
                              hipStream_t stream) {
    const float* pillars = (const float*)d_in[0];
    const int*   coors   = (const int*)d_in[1];
    const int*   npp     = (const int*)d_in[2];
    const float* W1 = (const float*)d_in[4];
    const float* g1 = (const float*)d_in[5];
    const float* b1 = (const float*)d_in[6];
    const float* m1 = (const float*)d_in[7];
    const float* v1 = (const float*)d_in[8];
    const float* W2 = (const float*)d_in[9];
    const float* g2 = (const float*)d_in[10];
    const float* b2 = (const float*)d_in[11];
    const float* m2 = (const float*)d_in[12];
    const float* v2 = (const float*)d_in[13];

    const int P = in_sizes[2];                       // 64000
    const int B = out_size / (COUT * YG * XG);       // 4

    float* pooled = (float*)d_ws;
    int*   winner = (int*)((char*)d_ws + (size_t)COUT * P * sizeof(float));

    // Fragment scratch lives in the tail of d_out (scatter overwrites it last).
    char* fragbase = (char*)d_out + (size_t)out_size * sizeof(float) - 11264;
    unsigned short* w1f  = (unsigned short*)fragbase;            // 2048 B
    unsigned short* w2f  = (unsigned short*)(fragbase + 2048);   // 8192 B
    float*          bb2v = (float*)(fragbase + 10240);           // 256 B

    const int nwin4 = (B * YG * XG) / 4;             // 214272
    precompute_kernel<<<(nwin4 + 255) / 256, 256, 0, stream>>>(
        W1, g1, b1, m1, v1, W2, g2, b2, m2, v2, w1f, w2f, bb2v,
        (int4*)winner, nwin4);

    pillar_mlp_kernel<<<(P + 7) / 8, 256, 0, stream>>>(
        pillars, coors, npp, w1f, w2f, bb2v, pooled, winner, P);

    scatter_kernel<<<B * YG, 256, 0, stream>>>(
        (const float4*)pooled, (const int4*)winner, (f32x4*)d_out);
}